// Round 13
// baseline (195.990 us; speedup 1.0000x reference)
//
#include <hip/hip_runtime.h>
#include <stdint.h>

typedef unsigned short u16;
typedef __bf16 bf16x8 __attribute__((ext_vector_type(8)));
typedef float f32x4 __attribute__((ext_vector_type(4)));
typedef float f32x16 __attribute__((ext_vector_type(16)));

#define B_ 4
#define T_ 2048
#define C_ 1024
#define NH_ 16
#define HD_ 64
#define M_ (B_ * T_)   // 8192
#define N1_ (3 * C_)   // 3072
#define NQK_ 2048      // q,k packed stride

__device__ inline u16 f2bf(float f) {
    uint32_t u = __float_as_uint(f);
    u += 0x7FFFu + ((u >> 16) & 1u);
    return (u16)(u >> 16);
}

__device__ inline bf16x8 ld_bf16x8(const u16* p) {
    return *(const bf16x8*)(const void*)p;
}

__device__ inline uint32_t cvtpk_bf16(float a, float b) {
    uint32_t r;
    asm("v_cvt_pk_bf16_f32 %0, %1, %2" : "=v"(r) : "v"(a), "v"(b));
    return r;
}

__device__ inline float exp2_fast(float x) {
    float r;
    asm("v_exp_f32 %0, %1" : "=v"(r) : "v"(x));
    return r;
}

// async global->LDS, 16B per lane; LDS dest must be linear lane*16
__device__ inline void gload16(const u16* g, u16* l) {
    __builtin_amdgcn_global_load_lds(
        (const __attribute__((address_space(1))) uint32_t*)g,
        (__attribute__((address_space(3))) uint32_t*)l, 16, 0, 0);
}

// ---------------- fp32 -> bf16 elementwise ----------------
__global__ void f32_to_bf16_k(const float* __restrict__ in, u16* __restrict__ out, int n) {
    int i = (blockIdx.x * blockDim.x + threadIdx.x) * 4;
    int stride = gridDim.x * blockDim.x * 4;
    for (; i < n; i += stride) {
        float4 v = *(const float4*)(in + i);
        uint2 o;
        o.x = (uint32_t)f2bf(v.x) | ((uint32_t)f2bf(v.y) << 16);
        o.y = (uint32_t)f2bf(v.z) | ((uint32_t)f2bf(v.w) << 16);
        *(uint2*)(out + i) = o;
    }
}

// ---------------- fp32 [R][Cc] -> bf16 transpose [Cc][R], scale out-rows < scaleRows ----------------
__global__ void transpose_f32_bf16_k(const float* __restrict__ in, u16* __restrict__ out,
                                     int R, int Cc, int scaleRows, float scale) {
    __shared__ float tile[32][33];
    int c0 = blockIdx.x * 32, r0 = blockIdx.y * 32;
    int tx = threadIdx.x, ty = threadIdx.y;  // block (32,8)
#pragma unroll
    for (int i = 0; i < 4; ++i)
        tile[ty + i * 8][tx] = in[(size_t)(r0 + ty + i * 8) * Cc + c0 + tx];
    __syncthreads();
#pragma unroll
    for (int i = 0; i < 4; ++i) {
        int orow = c0 + ty + i * 8;
        float v = tile[tx][ty + i * 8];
        if (orow < scaleRows) v *= scale;   // fold attn scale * log2(e) into Q weights
        out[(size_t)orow * R + r0 + tx] = f2bf(v);
    }
}

// ---------------- GEMM: C[M][N] = A[M][K] * Bt[N][K]^T ----------------
// 128x128 tile, BK=32, TWO waves/block (128 thr): wave w owns rows w*64..+63, ALL 128 cols.
// Per-wave 32 MFMA/K-step with 12 KB LDS reads (0.375 KB/MFMA vs 0.5 at 2x2 waves) ->
// 25% less LDS-read traffic (pipe was saturated at 94 B/cy vs 85 measured ceiling).
// 3-buffer LDS, depth-2 prefetch via global_load_lds, COUNTED s_waitcnt vmcnt(8)
// (8 loads/thread/tile), 1 raw barrier/K-step. LDS XOR-swizzle (T2): conflict-free reads.
// T1 XCD chunking: xcd=bid&7 owns an 8-M-tile slab. Bijective (nwg%8==0).
template <int MODE>
__global__ __launch_bounds__(128) void gemm_bt_k(const u16* __restrict__ A,
                                                 const u16* __restrict__ Bt,
                                                 void* __restrict__ Cp,
                                                 u16* __restrict__ Vp,
                                                 int M, int N, int K) {
    __shared__ u16 As[3][128 * 32];
    __shared__ u16 Bs[3][128 * 32];
    const int t = threadIdx.x;
    const int w = t >> 6, l = t & 63;
    const int lr = l & 15, lg = l >> 4;
    // XCD-chunked block remap (HW: block i -> XCD i%8)
    const int bid = blockIdx.x;
    const int xcd = bid & 7, j = bid >> 3;
    const int mt = xcd * 8 + (j & 7);
    const int nt = j >> 3;
    const int R0 = mt * 128, C0 = nt * 128;

    const int sr = t >> 2;                              // 0..31
    const int sc = (((t & 3) ^ ((t >> 3) & 3)) * 8);    // source chunk pre-swizzled (same 64B line)
    const u16* Ag = A  + (size_t)(R0 + sr) * K + sc;
    const u16* Bg = Bt + (size_t)(C0 + sr) * K + sc;

    f32x4 acc[4][8] = {};
    const int nk = K / 32;

    // 8 gloads/thread/tile: rows sr+{0,32,64,96} of A and B (128 thr x 16B = 1024 u16 each)
#define STAGE(KT, BI)                                                             \
    do {                                                                          \
        gload16(Ag + (size_t)(KT) * 32,                   As[BI] + t * 8);        \
        gload16(Ag + (size_t)(KT) * 32 + (size_t)32 * K,  As[BI] + t * 8 + 1024); \
        gload16(Ag + (size_t)(KT) * 32 + (size_t)64 * K,  As[BI] + t * 8 + 2048); \
        gload16(Ag + (size_t)(KT) * 32 + (size_t)96 * K,  As[BI] + t * 8 + 3072); \
        gload16(Bg + (size_t)(KT) * 32,                   Bs[BI] + t * 8);        \
        gload16(Bg + (size_t)(KT) * 32 + (size_t)32 * K,  Bs[BI] + t * 8 + 1024); \
        gload16(Bg + (size_t)(KT) * 32 + (size_t)64 * K,  Bs[BI] + t * 8 + 2048); \
        gload16(Bg + (size_t)(KT) * 32 + (size_t)96 * K,  Bs[BI] + t * 8 + 3072); \
    } while (0)

    STAGE(0, 0);
    if (nk > 1) STAGE(1, 1);

    // swizzled read chunk: (lg ^ ((row>>1)&3))*8; (row>>1)&3 == (lr>>1)&3 for all mi/nj
    const int lg8 = (lg * 8) ^ (((lr >> 1) & 3) * 8);

    int bi = 0;
    for (int kt = 0; kt < nk; ++kt) {
        // newest-8 outstanding = tile kt+1; vmcnt(8) -> tile kt's 8 loads complete.
        if (kt + 1 < nk) asm volatile("s_waitcnt vmcnt(8)" ::: "memory");
        else             asm volatile("s_waitcnt vmcnt(0)" ::: "memory");
        __builtin_amdgcn_s_barrier();          // all waves: tile kt visible, prior reads done
        __builtin_amdgcn_sched_barrier(0);     // fence: no ds_read hoisted above the wait
        if (kt + 2 < nk) {
            int bn = bi + 2; if (bn >= 3) bn -= 3;
            STAGE(kt + 2, bn);                 // overwrites buffer read in iter kt-1 (barrier'd)
        }

        const u16* Ab = As[bi];
        const u16* Bb = Bs[bi];
        bf16x8 af[4], bfr[8];
#pragma unroll
        for (int mi = 0; mi < 4; ++mi)
            af[mi] = ld_bf16x8(Ab + (w * 64 + mi * 16 + lr) * 32 + lg8);
#pragma unroll
        for (int nj = 0; nj < 8; ++nj)
            bfr[nj] = ld_bf16x8(Bb + (nj * 16 + lr) * 32 + lg8);
        __builtin_amdgcn_s_setprio(1);
#pragma unroll
        for (int mi = 0; mi < 4; ++mi)
#pragma unroll
            for (int nj = 0; nj < 8; ++nj)
                acc[mi][nj] = __builtin_amdgcn_mfma_f32_16x16x32_bf16(af[mi], bfr[nj],
                                                                      acc[mi][nj], 0, 0, 0);
        __builtin_amdgcn_s_setprio(0);
        bi = (bi + 1 == 3) ? 0 : bi + 1;
    }
#undef STAGE

    if (MODE == 2 && C0 >= 2048) {
#pragma unroll
        for (int mi = 0; mi < 4; ++mi) {
            int row = R0 + w * 64 + mi * 16 + lg * 4;
            int bb = row >> 11, tt = row & 2047;
#pragma unroll
            for (int nj = 0; nj < 8; ++nj) {
                int cv = C0 - 2048 + nj * 16 + lr;
                int hh = cv >> 6, dd = cv & 63;
                ushort4 pk;
                pk.x = f2bf(acc[mi][nj][0]);
                pk.y = f2bf(acc[mi][nj][1]);
                pk.z = f2bf(acc[mi][nj][2]);
                pk.w = f2bf(acc[mi][nj][3]);
                *(ushort4*)(Vp + (((size_t)bb * NH_ + hh) * HD_ + dd) * (size_t)T_ + tt) = pk;
            }
        }
    } else {
#pragma unroll
        for (int mi = 0; mi < 4; ++mi) {
            int row = R0 + w * 64 + mi * 16 + lg * 4;
#pragma unroll
            for (int nj = 0; nj < 8; ++nj) {
                int col = C0 + nj * 16 + lr;
#pragma unroll
                for (int r = 0; r < 4; ++r) {
                    if (MODE == 0)
                        ((float*)Cp)[(size_t)(row + r) * N + col] = acc[mi][nj][r];
                    else
                        ((u16*)Cp)[(size_t)(row + r) * NQK_ + col] = f2bf(acc[mi][nj][r]);
                }
            }
        }
    }
}

// ---------------- fused causal flash attention ----------------
// 1024 blocks x 256 thr (4 waves of 32 q-rows, shared K/V staging). One (bh, J) job per
// block; heavy bands dispatched first (J = 15 - lin>>6) -> LPT backfill balances CUs.
// __launch_bounds__(256,3): 3 blocks/CU co-resident (LDS 3x32KB, VGPR<=170).
// K/V staged via global_load_lds (linear dest, source pre-XOR-swizzled), double-buffered,
// 1 barrier/tile. Register softmax in exp2 domain with defer-max; P built in-register.
__global__ __launch_bounds__(256, 3) void attn_fwd_k(const u16* __restrict__ qk,   // [B*T][2048]
                                                     const u16* __restrict__ vT,   // [b][h][d][t]
                                                     u16* __restrict__ attO) {
    __shared__ u16 Ks[2][64 * 64];   // [kv][d], byte(row,d) = row*128 + (d*2 ^ ((row&7)<<4))
    __shared__ u16 Vs[2][64 * 64];   // [d][kv], same swizzle on kv

    const int t = threadIdx.x;
    const int w = t >> 6, l = t & 63;
    const int r0 = l & 31, hi = l >> 5;
    // XCD-locality: lin%8 -> XCD serves 8 fixed heads (4MB K+V ~= one L2)
    const int lin = blockIdx.x;
    const int bh = (lin & 7) * 8 + ((lin >> 3) & 7);
    const int J = 15 - (lin >> 6);                 // heavy 128-row q-tile bands first
    const int b = bh >> 4, h = bh & 15;
    const u16* qkB = qk + (size_t)b * T_ * NQK_;

    // staging geometry: thread t covers rows sr, sr+32; 16B chunk (t&7), source pre-swizzled
    const int sr = t >> 3;                          // 0..31
    const int sof = ((t & 7) * 8) ^ ((sr & 7) << 3);
    const u16* gK = qkB + (size_t)sr * NQK_ + C_ + h * HD_ + sof;
    const u16* gV = vT + ((size_t)bh * HD_ + sr) * (size_t)T_ + sof;

    const int qW = J * 128 + w * 32;
    const int nt = 2 * J + 2;

    // Q B-fragments: col=q=lane&31, k=d (0.125*log2e pre-folded into weights)
    bf16x8 qf[4];
    {
        const u16* qp = qkB + (size_t)(qW + r0) * NQK_ + h * HD_ + hi * 8;
#pragma unroll
        for (int dc = 0; dc < 4; ++dc) qf[dc] = ld_bf16x8(qp + dc * 16);
    }

    f32x16 acc0 = {}, acc1 = {};   // O^T d-blocks [0..31],[32..63]; lane col = q
    float m = -1e30f, lsum = 0.f;

    // prologue: stage tile 0 -> buf 0
    gload16(gK, Ks[0] + t * 8);
    gload16(gK + (size_t)32 * NQK_, Ks[0] + t * 8 + 2048);
    gload16(gV, Vs[0] + t * 8);
    gload16(gV + (size_t)32 * T_, Vs[0] + t * 8 + 2048);
    __syncthreads();

    for (int kt = 0; kt < nt; ++kt) {
        const int kv = kt * 64;
        // prefetch next tile into other buffer (lands during compute, drained at barrier)
        if (kt + 1 < nt) {
            u16* dK = Ks[(kt + 1) & 1];
            u16* dV = Vs[(kt + 1) & 1];
            gload16(gK + (size_t)(kv + 64) * NQK_, dK + t * 8);
            gload16(gK + (size_t)(kv + 96) * NQK_, dK + t * 8 + 2048);
            gload16(gV + (kv + 64), dV + t * 8);
            gload16(gV + (size_t)32 * T_ + (kv + 64), dV + t * 8 + 2048);
        }
        const u16* Kb = Ks[kt & 1];
        const u16* Vb = Vs[kt & 1];

        if (kv <= qW) {                          // wave-uniform: wave has unmasked work
            const bool diag = (kv + 64 > qW);    // wave's own diagonal tile
            const bool up = (!diag) || (w & 1);  // upper 32 kv rows relevant?

            // ---- S^T = K * Q^T (A-frag rows=kv from LDS, swizzled read) ----
            f32x16 s0 = {}, s1 = {};
            __builtin_amdgcn_s_setprio(1);
#pragma unroll
            for (int dc = 0; dc < 4; ++dc) {
                int off = (dc * 32 + hi * 16) ^ ((r0 & 7) << 4);
                bf16x8 k0 = ld_bf16x8((const u16*)((const char*)Kb + r0 * 128 + off));
                s0 = __builtin_amdgcn_mfma_f32_32x32x16_bf16(k0, qf[dc], s0, 0, 0, 0);
                if (up) {
                    bf16x8 k1 = ld_bf16x8((const u16*)((const char*)Kb + r0 * 128 + 4096 + off));
                    s1 = __builtin_amdgcn_mfma_f32_32x32x16_bf16(k1, qf[dc], s1, 0, 0, 0);
                }
            }
            __builtin_amdgcn_s_setprio(0);

            // ---- causal mask (diag only): lane q = qW+r0, kv_local = (rg&3)+8*(rg>>2)+4*hi
            if (diag) {
                int qrel = qW + r0 - kv;
#pragma unroll
                for (int rg = 0; rg < 16; ++rg) {
                    int kv0 = (rg & 3) + 8 * (rg >> 2) + hi * 4;
                    s0[rg] = (kv0 > qrel) ? -1e30f : s0[rg];
                    if (up) s1[rg] = (kv0 + 32 > qrel) ? -1e30f : s1[rg];
                }
            }

            // ---- online softmax (exp2 domain) ----
            float a4[8];
            if (up) {
#pragma unroll
                for (int i = 0; i < 8; ++i)
                    a4[i] = fmaxf(fmaxf(s0[i], s0[i + 8]), fmaxf(s1[i], s1[i + 8]));
            } else {
#pragma unroll
                for (int i = 0; i < 8; ++i) a4[i] = fmaxf(s0[i], s0[i + 8]);
            }
#pragma unroll
            for (int i = 0; i < 4; ++i) a4[i] = fmaxf(a4[i], a4[i + 4]);
            float mx = fmaxf(fmaxf(a4[0], a4[1]), fmaxf(a4[2], a4[3]));
            mx = fmaxf(mx, __shfl_xor(mx, 32));

            if (!__all(mx - m <= 8.f)) {            // defer-max (T13)
                float mn = fmaxf(m, mx);
                float corr = exp2_fast(m - mn);
                m = mn;
                lsum *= corr;
#pragma unroll
                for (int rg = 0; rg < 16; ++rg) { acc0[rg] *= corr; acc1[rg] *= corr; }
            }
#pragma unroll
            for (int rg = 0; rg < 16; ++rg) s0[rg] = exp2_fast(s0[rg] - m);
            if (up) {
#pragma unroll
                for (int rg = 0; rg < 16; ++rg) s1[rg] = exp2_fast(s1[rg] - m);
            }
            float sb[8];
            if (up) {
#pragma unroll
                for (int i = 0; i < 8; ++i) sb[i] = (s0[i] + s0[i + 8]) + (s1[i] + s1[i + 8]);
            } else {
#pragma unroll
                for (int i = 0; i < 8; ++i) sb[i] = s0[i] + s0[i + 8];
            }
#pragma unroll
            for (int i = 0; i < 4; ++i) sb[i] += sb[i + 4];
            float rs = (sb[0] + sb[1]) + (sb[2] + sb[3]);
            rs += __shfl_xor(rs, 32);
            lsum += rs;

            // ---- P^T B-fragments in-register ----
            bf16x8 pb0, pb1, pb2, pb3;
            {
                uint32_t c0 = cvtpk_bf16(s0[0], s0[1]),   c1 = cvtpk_bf16(s0[2], s0[3]);
                uint32_t c2 = cvtpk_bf16(s0[4], s0[5]),   c3 = cvtpk_bf16(s0[6], s0[7]);
                uint32_t c4 = cvtpk_bf16(s0[8], s0[9]),   c5 = cvtpk_bf16(s0[10], s0[11]);
                uint32_t c6 = cvtpk_bf16(s0[12], s0[13]), c7 = cvtpk_bf16(s0[14], s0[15]);
                uint32_t x0 = (uint32_t)__shfl_xor((int)c0, 32), x1 = (uint32_t)__shfl_xor((int)c1, 32);
                uint32_t x2 = (uint32_t)__shfl_xor((int)c2, 32), x3 = (uint32_t)__shfl_xor((int)c3, 32);
                uint32_t x4 = (uint32_t)__shfl_xor((int)c4, 32), x5 = (uint32_t)__shfl_xor((int)c5, 32);
                uint32_t x6 = (uint32_t)__shfl_xor((int)c6, 32), x7 = (uint32_t)__shfl_xor((int)c7, 32);
                union { uint32_t u[4]; bf16x8 v; } f0, f1;
                f0.u[0] = hi ? x2 : c0;  f0.u[1] = hi ? x3 : c1;
                f0.u[2] = hi ? c2 : x0;  f0.u[3] = hi ? c3 : x1;
                f1.u[0] = hi ? x6 : c4;  f1.u[1] = hi ? x7 : c5;
                f1.u[2] = hi ? c6 : x4;  f1.u[3] = hi ? c7 : x5;
                pb0 = f0.v; pb1 = f1.v;
            }
            if (up) {
                uint32_t c0 = cvtpk_bf16(s1[0], s1[1]),   c1 = cvtpk_bf16(s1[2], s1[3]);
                uint32_t c2 = cvtpk_bf16(s1[4], s1[5]),   c3 = cvtpk_bf16(s1[6], s1[7]);
                uint32_t c4 = cvtpk_bf16(s1[8], s1[9]),   c5 = cvtpk_bf16(s1[10], s1[11]);
                uint32_t c6 = cvtpk_bf16(s1[12], s1[13]), c7 = cvtpk_bf16(s1[14], s1[15]);
                uint32_t x0 = (uint32_t)__shfl_xor((int)c0, 32), x1 = (uint32_t)__shfl_xor((int)c1, 32);
                uint32_t x2 = (uint32_t)__shfl_xor((int)c2, 32), x3 = (uint32_t)__shfl_xor((int)c3, 32);
                uint32_t x4 = (uint32_t)__shfl_xor((int)c4, 32), x5 = (uint32_t)__shfl_xor((int)c5, 32);
                uint32_t x6 = (uint32_t)__shfl_xor((int)c6, 32), x7 = (uint32_t)__shfl_xor((int)c7, 32);
                union { uint32_t u[4]; bf16x8 v; } f0, f1;
                f0.u[0] = hi ? x2 : c0;  f0.u[1] = hi ? x3 : c1;
                f0.u[2] = hi ? c2 : x0;  f0.u[3] = hi ? c3 : x1;
                f1.u[0] = hi ? x6 : c4;  f1.u[1] = hi ? x7 : c5;
                f1.u[2] = hi ? c6 : x4;  f1.u[3] = hi ? c7 : x5;
                pb2 = f0.v; pb3 = f1.v;
            }

            // ---- O^T += V^T * P^T (A-frag rows=d from LDS, swizzled read) ----
            __builtin_amdgcn_s_setprio(1);
            {
                int off0 = (hi * 16) ^ ((r0 & 7) << 4);
                int off1 = (32 + hi * 16) ^ ((r0 & 7) << 4);
                bf16x8 va0 = ld_bf16x8((const u16*)((const char*)Vb + r0 * 128 + off0));
                bf16x8 va1 = ld_bf16x8((const u16*)((const char*)Vb + r0 * 128 + off1));
                bf16x8 vb0 = ld_bf16x8((const u16*)((const char*)Vb + r0 * 128 + 4096 + off0));
                bf16x8 vb1 = ld_bf16x8((const u16*)((const char*)Vb + r0 * 128 + 4096 + off1));
                acc0 = __builtin_amdgcn_mfma_f32_32x32x16_bf16(va0, pb0, acc0, 0, 0, 0);
                acc0 = __builtin_amdgcn_mfma_f32_32x32x16_bf16(va1, pb1, acc0, 0, 0, 0);
                acc1 = __builtin_amdgcn_mfma_f32_32x32x16_bf16(vb0, pb0, acc1, 0, 0, 0);
                acc1 = __builtin_amdgcn_mfma_f32_32x32x16_bf16(vb1, pb1, acc1, 0, 0, 0);
                if (up) {
                    int off2 = (64 + hi * 16) ^ ((r0 & 7) << 4);
                    int off3 = (96 + hi * 16) ^ ((r0 & 7) << 4);
                    bf16x8 va2 = ld_bf16x8((const u16*)((const char*)Vb + r0 * 128 + off2));
                    bf16x8 va3 = ld_bf16x8((const u16*)((const char*)Vb + r0 * 128 + off3));
                    bf16x8 vb2 = ld_bf16x8((const u16*)((const char*)Vb + r0 * 128 + 4096 + off2));
                    bf16x8 vb3 = ld_bf16x8((const u16*)((const char*)Vb + r0 * 128 + 4096 + off3));
                    acc0 = __builtin_amdgcn_mfma_f32_32x32x16_bf16(va2, pb2, acc0, 0, 0, 0);
                    acc0 = __builtin_amdgcn_mfma_f32_32x32x16_bf16(va3, pb3, acc0, 0, 0, 0);
                    acc1 = __builtin_amdgcn_mfma_f32_32x32x16_bf16(vb2, pb2, acc1, 0, 0, 0);
                    acc1 = __builtin_amdgcn_mfma_f32_32x32x16_bf16(vb3, pb3, acc1, 0, 0, 0);
                }
            }
            __builtin_amdgcn_s_setprio(0);
        }

        __syncthreads();   // drains prefetch gloads + all ds reads of this buffer
    }

    // epilogue: lane holds O[q=qW+r0][d = db*32 + 8g + 4*hi + r]
    float inv = 1.0f / lsum;
    u16* op = attO + ((size_t)b * T_ + qW + r0) * C_ + h * HD_;
#pragma unroll
    for (int g = 0; g < 4; ++g) {
        int d0 = g * 8 + hi * 4;
        ushort4 p0, p1;
        p0.x = f2bf(acc0[4 * g + 0] * inv);
        p0.y = f2bf(acc0[4 * g + 1] * inv);
        p0.z = f2bf(acc0[4 * g + 2] * inv);
        p0.w = f2bf(acc0[4 * g + 3] * inv);
        *(ushort4*)(op + d0) = p0;
        p1.x = f2bf(acc1[4 * g + 0] * inv);
        p1.y = f2bf(acc1[4 * g + 1] * inv);
        p1.z = f2bf(acc1[4 * g + 2] * inv);
        p1.w = f2bf(acc1[4 * g + 3] * inv);
        *(ushort4*)(op + 32 + d0) = p1;
    }
}

extern "C" void kernel_launch(void* const* d_in, const int* in_sizes, int n_in,
                              void* d_out, int out_size, void* d_ws, size_t ws_size,
                              hipStream_t stream) {
    const float* x      = (const float*)d_in[0];
    const float* w_attn = (const float*)d_in[1];
    const float* w_proj = (const float*)d_in[2];
    float* out = (float*)d_out;

    char* ws = (char*)d_ws;
    const size_t SZ_XB = (size_t)M_ * C_ * 2;       // 16.78 MB
    const size_t SZ_WA = (size_t)C_ * N1_ * 2;      //  6.29 MB
    const size_t SZ_WP = (size_t)C_ * C_ * 2;       //  2.10 MB
    const size_t SZ_QK = (size_t)M_ * NQK_ * 2;     // 33.55 MB
    const size_t SZ_VT = (size_t)M_ * C_ * 2;       // 16.78 MB
    u16* xb   = (u16*)ws;
    u16* waT  = (u16*)(ws + SZ_XB);
    u16* wpT  = (u16*)(ws + SZ_XB + SZ_WA);
    u16* qkb  = (u16*)(ws + SZ_XB + SZ_WA + SZ_WP);
    u16* vtb  = (u16*)(ws + SZ_XB + SZ_WA + SZ_WP + SZ_QK);
    u16* attO = (u16*)(ws + SZ_XB + SZ_WA + SZ_WP + SZ_QK + SZ_VT);

    f32_to_bf16_k<<<2048, 256, 0, stream>>>(x, xb, M_ * C_);
    dim3 tb(32, 8);
    // Q weights carry 0.125 * log2(e) so attention works in exp2 domain
    transpose_f32_bf16_k<<<dim3(N1_ / 32, C_ / 32), tb, 0, stream>>>(w_attn, waT, C_, N1_, C_,
                                                                     0.125f * 1.44269504088896f);
    transpose_f32_bf16_k<<<dim3(C_ / 32, C_ / 32), tb, 0, stream>>>(w_proj, wpT, C_, C_, 0, 1.0f);

    gemm_bt_k<2><<<dim3((M_ / 128) * (N1_ / 128)), 128, 0, stream>>>(xb, waT, qkb, vtb, M_, N1_, C_);
    attn_fwd_k<<<dim3(1024), 256, 0, stream>>>(qkb, vtb, attO);
    gemm_bt_k<0><<<dim3((M_ / 128) * (C_ / 128)), 128, 0, stream>>>(attO, wpT, out, nullptr, M_, C_, C_);
}

// Round 14
// 184.065 us; speedup vs baseline: 1.0648x; 1.0648x over previous
//
#include <hip/hip_runtime.h>
#include <stdint.h>

typedef unsigned short u16;
typedef __bf16 bf16x8 __attribute__((ext_vector_type(8)));
typedef float f32x4 __attribute__((ext_vector_type(4)));
typedef float f32x16 __attribute__((ext_vector_type(16)));

#define B_ 4
#define T_ 2048
#define C_ 1024
#define NH_ 16
#define HD_ 64
#define M_ (B_ * T_)   // 8192
#define N1_ (3 * C_)   // 3072
#define NQK_ 2048      // q,k packed stride

__device__ inline u16 f2bf(float f) {
    uint32_t u = __float_as_uint(f);
    u += 0x7FFFu + ((u >> 16) & 1u);
    return (u16)(u >> 16);
}

__device__ inline bf16x8 ld_bf16x8(const u16* p) {
    return *(const bf16x8*)(const void*)p;
}

__device__ inline uint32_t cvtpk_bf16(float a, float b) {
    uint32_t r;
    asm("v_cvt_pk_bf16_f32 %0, %1, %2" : "=v"(r) : "v"(a), "v"(b));
    return r;
}

__device__ inline float exp2_fast(float x) {
    float r;
    asm("v_exp_f32 %0, %1" : "=v"(r) : "v"(x));
    return r;
}

// async global->LDS, 16B per lane; LDS dest must be linear lane*16
__device__ inline void gload16(const u16* g, u16* l) {
    __builtin_amdgcn_global_load_lds(
        (const __attribute__((address_space(1))) uint32_t*)g,
        (__attribute__((address_space(3))) uint32_t*)l, 16, 0, 0);
}

// ---------------- fp32 -> bf16 elementwise ----------------
__global__ void f32_to_bf16_k(const float* __restrict__ in, u16* __restrict__ out, int n) {
    int i = (blockIdx.x * blockDim.x + threadIdx.x) * 4;
    int stride = gridDim.x * blockDim.x * 4;
    for (; i < n; i += stride) {
        float4 v = *(const float4*)(in + i);
        uint2 o;
        o.x = (uint32_t)f2bf(v.x) | ((uint32_t)f2bf(v.y) << 16);
        o.y = (uint32_t)f2bf(v.z) | ((uint32_t)f2bf(v.w) << 16);
        *(uint2*)(out + i) = o;
    }
}

// ---------------- fp32 [R][Cc] -> bf16 transpose [Cc][R], scale out-rows < scaleRows ----------------
__global__ void transpose_f32_bf16_k(const float* __restrict__ in, u16* __restrict__ out,
                                     int R, int Cc, int scaleRows, float scale) {
    __shared__ float tile[32][33];
    int c0 = blockIdx.x * 32, r0 = blockIdx.y * 32;
    int tx = threadIdx.x, ty = threadIdx.y;  // block (32,8)
#pragma unroll
    for (int i = 0; i < 4; ++i)
        tile[ty + i * 8][tx] = in[(size_t)(r0 + ty + i * 8) * Cc + c0 + tx];
    __syncthreads();
#pragma unroll
    for (int i = 0; i < 4; ++i) {
        int orow = c0 + ty + i * 8;
        float v = tile[tx][ty + i * 8];
        if (orow < scaleRows) v *= scale;   // fold attn scale * log2(e) into Q weights
        out[(size_t)orow * R + r0 + tx] = f2bf(v);
    }
}

// ---------------- GEMM: C[M][N] = A[M][K] * Bt[N][K]^T ----------------
// 128x128 tile, BK=32, 3-buffer LDS, depth-2 prefetch via global_load_lds,
// COUNTED s_waitcnt vmcnt(4), 1 raw barrier/K-step.
// LDS XOR-swizzle (T2): 16B chunk c of row r stored at chunk c^((r>>1)&3); conflict-free reads.
// T1 XCD chunking: 1-D grid, xcd=bid&7 owns an 8-M-tile slab (A-slice 2MB -> L2-resident),
// walks N-tiles with each B-tile reused by 8 consecutive blocks. Bijective (nwg%8==0).
template <int MODE>
__global__ __launch_bounds__(256) void gemm_bt_k(const u16* __restrict__ A,
                                                 const u16* __restrict__ Bt,
                                                 void* __restrict__ Cp,
                                                 u16* __restrict__ Vp,
                                                 int M, int N, int K) {
    __shared__ u16 As[3][128 * 32];
    __shared__ u16 Bs[3][128 * 32];
    const int t = threadIdx.x;
    const int w = t >> 6, l = t & 63;
    const int wr = w >> 1, wc = w & 1;
    const int lr = l & 15, lg = l >> 4;
    // XCD-chunked block remap (HW: block i -> XCD i%8)
    const int bid = blockIdx.x;
    const int xcd = bid & 7, j = bid >> 3;
    const int mt = xcd * 8 + (j & 7);     // M-tile within this XCD's slab
    const int nt = j >> 3;                // N-tile, advances every 8 blocks
    const int R0 = mt * 128, C0 = nt * 128;

    const int sr = t >> 2;
    const int sc = (((t & 3) ^ ((t >> 3) & 3)) * 8);   // source chunk pre-swizzled (same 64B line)
    const u16* Ag  = A  + (size_t)(R0 + sr) * K + sc;
    const u16* Ag2 = Ag + (size_t)64 * K;
    const u16* Bg  = Bt + (size_t)(C0 + sr) * K + sc;
    const u16* Bg2 = Bg + (size_t)64 * K;

    f32x4 acc[4][4] = {};
    const int nk = K / 32;

#define STAGE(KT, BI)                                               \
    do {                                                            \
        gload16(Ag  + (size_t)(KT) * 32, As[BI] + t * 8);           \
        gload16(Ag2 + (size_t)(KT) * 32, As[BI] + t * 8 + 2048);    \
        gload16(Bg  + (size_t)(KT) * 32, Bs[BI] + t * 8);           \
        gload16(Bg2 + (size_t)(KT) * 32, Bs[BI] + t * 8 + 2048);    \
    } while (0)

    STAGE(0, 0);
    if (nk > 1) STAGE(1, 1);

    // swizzled read chunk: (lg ^ ((row>>1)&3))*8; (row>>1)&3 == (lr>>1)&3 for all mi/nj
    const int lg8 = (lg * 8) ^ (((lr >> 1) & 3) * 8);

    int bi = 0;
    for (int kt = 0; kt < nk; ++kt) {
        if (kt + 1 < nk) asm volatile("s_waitcnt vmcnt(4)" ::: "memory");
        else             asm volatile("s_waitcnt vmcnt(0)" ::: "memory");
        __builtin_amdgcn_s_barrier();
        __builtin_amdgcn_sched_barrier(0);
        if (kt + 2 < nk) {
            int bn = bi + 2; if (bn >= 3) bn -= 3;
            STAGE(kt + 2, bn);
        }

        const u16* Ab = As[bi];
        const u16* Bb = Bs[bi];
        bf16x8 af[4], bfr[4];
#pragma unroll
        for (int mi = 0; mi < 4; ++mi)
            af[mi] = ld_bf16x8(Ab + (wr * 64 + mi * 16 + lr) * 32 + lg8);
#pragma unroll
        for (int nj = 0; nj < 4; ++nj)
            bfr[nj] = ld_bf16x8(Bb + (wc * 64 + nj * 16 + lr) * 32 + lg8);
        __builtin_amdgcn_s_setprio(1);
#pragma unroll
        for (int mi = 0; mi < 4; ++mi)
#pragma unroll
            for (int nj = 0; nj < 4; ++nj)
                acc[mi][nj] = __builtin_amdgcn_mfma_f32_16x16x32_bf16(af[mi], bfr[nj],
                                                                      acc[mi][nj], 0, 0, 0);
        __builtin_amdgcn_s_setprio(0);
        bi = (bi + 1 == 3) ? 0 : bi + 1;
    }
#undef STAGE

    if (MODE == 2 && C0 >= 2048) {
#pragma unroll
        for (int mi = 0; mi < 4; ++mi) {
            int row = R0 + wr * 64 + mi * 16 + lg * 4;
            int bb = row >> 11, tt = row & 2047;
#pragma unroll
            for (int nj = 0; nj < 4; ++nj) {
                int cv = C0 - 2048 + wc * 64 + nj * 16 + lr;
                int hh = cv >> 6, dd = cv & 63;
                ushort4 pk;
                pk.x = f2bf(acc[mi][nj][0]);
                pk.y = f2bf(acc[mi][nj][1]);
                pk.z = f2bf(acc[mi][nj][2]);
                pk.w = f2bf(acc[mi][nj][3]);
                *(ushort4*)(Vp + (((size_t)bb * NH_ + hh) * HD_ + dd) * (size_t)T_ + tt) = pk;
            }
        }
    } else {
#pragma unroll
        for (int mi = 0; mi < 4; ++mi) {
            int row = R0 + wr * 64 + mi * 16 + lg * 4;
#pragma unroll
            for (int nj = 0; nj < 4; ++nj) {
                int col = C0 + wc * 64 + nj * 16 + lr;
#pragma unroll
                for (int r = 0; r < 4; ++r) {
                    if (MODE == 0)
                        ((float*)Cp)[(size_t)(row + r) * N + col] = acc[mi][nj][r];
                    else
                        ((u16*)Cp)[(size_t)(row + r) * NQK_ + col] = f2bf(acc[mi][nj][r]);
                }
            }
        }
    }
}

// ---------------- fused causal flash attention ----------------
// 1024 blocks x 256 thr (4 waves of 32 q-rows, shared K/V staging). One (bh, J) job per
// block; heavy bands dispatched first (J = 15 - lin>>6) -> LPT backfill balances CUs.
// __launch_bounds__(256,3): 3 blocks/CU co-resident (LDS 3x32KB, VGPR<=170).
// K/V staged via global_load_lds (linear dest, source pre-XOR-swizzled), double-buffered,
// 1 barrier/tile. Register softmax in exp2 domain with defer-max; P built in-register.
__global__ __launch_bounds__(256, 3) void attn_fwd_k(const u16* __restrict__ qk,   // [B*T][2048]
                                                     const u16* __restrict__ vT,   // [b][h][d][t]
                                                     u16* __restrict__ attO) {
    __shared__ u16 Ks[2][64 * 64];   // [kv][d], byte(row,d) = row*128 + (d*2 ^ ((row&7)<<4))
    __shared__ u16 Vs[2][64 * 64];   // [d][kv], same swizzle on kv

    const int t = threadIdx.x;
    const int w = t >> 6, l = t & 63;
    const int r0 = l & 31, hi = l >> 5;
    // XCD-locality: lin%8 -> XCD serves 8 fixed heads (4MB K+V ~= one L2)
    const int lin = blockIdx.x;
    const int bh = (lin & 7) * 8 + ((lin >> 3) & 7);
    const int J = 15 - (lin >> 6);                 // heavy 128-row q-tile bands first
    const int b = bh >> 4, h = bh & 15;
    const u16* qkB = qk + (size_t)b * T_ * NQK_;

    // staging geometry: thread t covers rows sr, sr+32; 16B chunk (t&7), source pre-swizzled
    const int sr = t >> 3;                          // 0..31
    const int sof = ((t & 7) * 8) ^ ((sr & 7) << 3);
    const u16* gK = qkB + (size_t)sr * NQK_ + C_ + h * HD_ + sof;
    const u16* gV = vT + ((size_t)bh * HD_ + sr) * (size_t)T_ + sof;

    const int qW = J * 128 + w * 32;
    const int nt = 2 * J + 2;

    // Q B-fragments: col=q=lane&31, k=d (0.125*log2e pre-folded into weights)
    bf16x8 qf[4];
    {
        const u16* qp = qkB + (size_t)(qW + r0) * NQK_ + h * HD_ + hi * 8;
#pragma unroll
        for (int dc = 0; dc < 4; ++dc) qf[dc] = ld_bf16x8(qp + dc * 16);
    }

    f32x16 acc0 = {}, acc1 = {};   // O^T d-blocks [0..31],[32..63]; lane col = q
    float m = -1e30f, lsum = 0.f;

    // prologue: stage tile 0 -> buf 0
    gload16(gK, Ks[0] + t * 8);
    gload16(gK + (size_t)32 * NQK_, Ks[0] + t * 8 + 2048);
    gload16(gV, Vs[0] + t * 8);
    gload16(gV + (size_t)32 * T_, Vs[0] + t * 8 + 2048);
    __syncthreads();

    for (int kt = 0; kt < nt; ++kt) {
        const int kv = kt * 64;
        // prefetch next tile into other buffer (lands during compute, drained at barrier)
        if (kt + 1 < nt) {
            u16* dK = Ks[(kt + 1) & 1];
            u16* dV = Vs[(kt + 1) & 1];
            gload16(gK + (size_t)(kv + 64) * NQK_, dK + t * 8);
            gload16(gK + (size_t)(kv + 96) * NQK_, dK + t * 8 + 2048);
            gload16(gV + (kv + 64), dV + t * 8);
            gload16(gV + (size_t)32 * T_ + (kv + 64), dV + t * 8 + 2048);
        }
        const u16* Kb = Ks[kt & 1];
        const u16* Vb = Vs[kt & 1];

        if (kv <= qW) {                          // wave-uniform: wave has unmasked work
            const bool diag = (kv + 64 > qW);    // wave's own diagonal tile
            const bool up = (!diag) || (w & 1);  // upper 32 kv rows relevant?

            // ---- S^T = K * Q^T (A-frag rows=kv from LDS, swizzled read) ----
            f32x16 s0 = {}, s1 = {};
            __builtin_amdgcn_s_setprio(1);
#pragma unroll
            for (int dc = 0; dc < 4; ++dc) {
                int off = (dc * 32 + hi * 16) ^ ((r0 & 7) << 4);
                bf16x8 k0 = ld_bf16x8((const u16*)((const char*)Kb + r0 * 128 + off));
                s0 = __builtin_amdgcn_mfma_f32_32x32x16_bf16(k0, qf[dc], s0, 0, 0, 0);
                if (up) {
                    bf16x8 k1 = ld_bf16x8((const u16*)((const char*)Kb + r0 * 128 + 4096 + off));
                    s1 = __builtin_amdgcn_mfma_f32_32x32x16_bf16(k1, qf[dc], s1, 0, 0, 0);
                }
            }
            __builtin_amdgcn_s_setprio(0);

            // ---- causal mask (diag only): lane q = qW+r0, kv_local = (rg&3)+8*(rg>>2)+4*hi
            if (diag) {
                int qrel = qW + r0 - kv;
#pragma unroll
                for (int rg = 0; rg < 16; ++rg) {
                    int kv0 = (rg & 3) + 8 * (rg >> 2) + hi * 4;
                    s0[rg] = (kv0 > qrel) ? -1e30f : s0[rg];
                    if (up) s1[rg] = (kv0 + 32 > qrel) ? -1e30f : s1[rg];
                }
            }

            // ---- online softmax (exp2 domain) ----
            float a4[8];
            if (up) {
#pragma unroll
                for (int i = 0; i < 8; ++i)
                    a4[i] = fmaxf(fmaxf(s0[i], s0[i + 8]), fmaxf(s1[i], s1[i + 8]));
            } else {
#pragma unroll
                for (int i = 0; i < 8; ++i) a4[i] = fmaxf(s0[i], s0[i + 8]);
            }
#pragma unroll
            for (int i = 0; i < 4; ++i) a4[i] = fmaxf(a4[i], a4[i + 4]);
            float mx = fmaxf(fmaxf(a4[0], a4[1]), fmaxf(a4[2], a4[3]));
            mx = fmaxf(mx, __shfl_xor(mx, 32));

            if (!__all(mx - m <= 8.f)) {            // defer-max (T13)
                float mn = fmaxf(m, mx);
                float corr = exp2_fast(m - mn);
                m = mn;
                lsum *= corr;
#pragma unroll
                for (int rg = 0; rg < 16; ++rg) { acc0[rg] *= corr; acc1[rg] *= corr; }
            }
#pragma unroll
            for (int rg = 0; rg < 16; ++rg) s0[rg] = exp2_fast(s0[rg] - m);
            if (up) {
#pragma unroll
                for (int rg = 0; rg < 16; ++rg) s1[rg] = exp2_fast(s1[rg] - m);
            }
            float sb[8];
            if (up) {
#pragma unroll
                for (int i = 0; i < 8; ++i) sb[i] = (s0[i] + s0[i + 8]) + (s1[i] + s1[i + 8]);
            } else {
#pragma unroll
                for (int i = 0; i < 8; ++i) sb[i] = s0[i] + s0[i + 8];
            }
#pragma unroll
            for (int i = 0; i < 4; ++i) sb[i] += sb[i + 4];
            float rs = (sb[0] + sb[1]) + (sb[2] + sb[3]);
            rs += __shfl_xor(rs, 32);
            lsum += rs;

            // ---- P^T B-fragments in-register ----
            bf16x8 pb0, pb1, pb2, pb3;
            {
                uint32_t c0 = cvtpk_bf16(s0[0], s0[1]),   c1 = cvtpk_bf16(s0[2], s0[3]);
                uint32_t c2 = cvtpk_bf16(s0[4], s0[5]),   c3 = cvtpk_bf16(s0[6], s0[7]);
                uint32_t c4 = cvtpk_bf16(s0[8], s0[9]),   c5 = cvtpk_bf16(s0[10], s0[11]);
                uint32_t c6 = cvtpk_bf16(s0[12], s0[13]), c7 = cvtpk_bf16(s0[14], s0[15]);
                uint32_t x0 = (uint32_t)__shfl_xor((int)c0, 32), x1 = (uint32_t)__shfl_xor((int)c1, 32);
                uint32_t x2 = (uint32_t)__shfl_xor((int)c2, 32), x3 = (uint32_t)__shfl_xor((int)c3, 32);
                uint32_t x4 = (uint32_t)__shfl_xor((int)c4, 32), x5 = (uint32_t)__shfl_xor((int)c5, 32);
                uint32_t x6 = (uint32_t)__shfl_xor((int)c6, 32), x7 = (uint32_t)__shfl_xor((int)c7, 32);
                union { uint32_t u[4]; bf16x8 v; } f0, f1;
                f0.u[0] = hi ? x2 : c0;  f0.u[1] = hi ? x3 : c1;
                f0.u[2] = hi ? c2 : x0;  f0.u[3] = hi ? c3 : x1;
                f1.u[0] = hi ? x6 : c4;  f1.u[1] = hi ? x7 : c5;
                f1.u[2] = hi ? c6 : x4;  f1.u[3] = hi ? c7 : x5;
                pb0 = f0.v; pb1 = f1.v;
            }
            if (up) {
                uint32_t c0 = cvtpk_bf16(s1[0], s1[1]),   c1 = cvtpk_bf16(s1[2], s1[3]);
                uint32_t c2 = cvtpk_bf16(s1[4], s1[5]),   c3 = cvtpk_bf16(s1[6], s1[7]);
                uint32_t c4 = cvtpk_bf16(s1[8], s1[9]),   c5 = cvtpk_bf16(s1[10], s1[11]);
                uint32_t c6 = cvtpk_bf16(s1[12], s1[13]), c7 = cvtpk_bf16(s1[14], s1[15]);
                uint32_t x0 = (uint32_t)__shfl_xor((int)c0, 32), x1 = (uint32_t)__shfl_xor((int)c1, 32);
                uint32_t x2 = (uint32_t)__shfl_xor((int)c2, 32), x3 = (uint32_t)__shfl_xor((int)c3, 32);
                uint32_t x4 = (uint32_t)__shfl_xor((int)c4, 32), x5 = (uint32_t)__shfl_xor((int)c5, 32);
                uint32_t x6 = (uint32_t)__shfl_xor((int)c6, 32), x7 = (uint32_t)__shfl_xor((int)c7, 32);
                union { uint32_t u[4]; bf16x8 v; } f0, f1;
                f0.u[0] = hi ? x2 : c0;  f0.u[1] = hi ? x3 : c1;
                f0.u[2] = hi ? c2 : x0;  f0.u[3] = hi ? c3 : x1;
                f1.u[0] = hi ? x6 : c4;  f1.u[1] = hi ? x7 : c5;
                f1.u[2] = hi ? c6 : x4;  f1.u[3] = hi ? c7 : x5;
                pb2 = f0.v; pb3 = f1.v;
            }

            // ---- O^T += V^T * P^T (A-frag rows=d from LDS, swizzled read) ----
            __builtin_amdgcn_s_setprio(1);
            {
                int off0 = (hi * 16) ^ ((r0 & 7) << 4);
                int off1 = (32 + hi * 16) ^ ((r0 & 7) << 4);
                bf16x8 va0 = ld_bf16x8((const u16*)((const char*)Vb + r0 * 128 + off0));
                bf16x8 va1 = ld_bf16x8((const u16*)((const char*)Vb + r0 * 128 + off1));
                bf16x8 vb0 = ld_bf16x8((const u16*)((const char*)Vb + r0 * 128 + 4096 + off0));
                bf16x8 vb1 = ld_bf16x8((const u16*)((const char*)Vb + r0 * 128 + 4096 + off1));
                acc0 = __builtin_amdgcn_mfma_f32_32x32x16_bf16(va0, pb0, acc0, 0, 0, 0);
                acc0 = __builtin_amdgcn_mfma_f32_32x32x16_bf16(va1, pb1, acc0, 0, 0, 0);
                acc1 = __builtin_amdgcn_mfma_f32_32x32x16_bf16(vb0, pb0, acc1, 0, 0, 0);
                acc1 = __builtin_amdgcn_mfma_f32_32x32x16_bf16(vb1, pb1, acc1, 0, 0, 0);
                if (up) {
                    int off2 = (64 + hi * 16) ^ ((r0 & 7) << 4);
                    int off3 = (96 + hi * 16) ^ ((r0 & 7) << 4);
                    bf16x8 va2 = ld_bf16x8((const u16*)((const char*)Vb + r0 * 128 + off2));
                    bf16x8 va3 = ld_bf16x8((const u16*)((const char*)Vb + r0 * 128 + off3));
                    bf16x8 vb2 = ld_bf16x8((const u16*)((const char*)Vb + r0 * 128 + 4096 + off2));
                    bf16x8 vb3 = ld_bf16x8((const u16*)((const char*)Vb + r0 * 128 + 4096 + off3));
                    acc0 = __builtin_amdgcn_mfma_f32_32x32x16_bf16(va2, pb2, acc0, 0, 0, 0);
                    acc0 = __builtin_amdgcn_mfma_f32_32x32x16_bf16(va3, pb3, acc0, 0, 0, 0);
                    acc1 = __builtin_amdgcn_mfma_f32_32x32x16_bf16(vb2, pb2, acc1, 0, 0, 0);
                    acc1 = __builtin_amdgcn_mfma_f32_32x32x16_bf16(vb3, pb3, acc1, 0, 0, 0);
                }
            }
            __builtin_amdgcn_s_setprio(0);
        }

        __syncthreads();   // drains prefetch gloads + all ds reads of this buffer
    }

    // epilogue: lane holds O[q=qW+r0][d = db*32 + 8g + 4*hi + r]
    float inv = 1.0f / lsum;
    u16* op = attO + ((size_t)b * T_ + qW + r0) * C_ + h * HD_;
#pragma unroll
    for (int g = 0; g < 4; ++g) {
        int d0 = g * 8 + hi * 4;
        ushort4 p0, p1;
        p0.x = f2bf(acc0[4 * g + 0] * inv);
        p0.y = f2bf(acc0[4 * g + 1] * inv);
        p0.z = f2bf(acc0[4 * g + 2] * inv);
        p0.w = f2bf(acc0[4 * g + 3] * inv);
        *(ushort4*)(op + d0) = p0;
        p1.x = f2bf(acc1[4 * g + 0] * inv);
        p1.y = f2bf(acc1[4 * g + 1] * inv);
        p1.z = f2bf(acc1[4 * g + 2] * inv);
        p1.w = f2bf(acc1[4 * g + 3] * inv);
        *(ushort4*)(op + 32 + d0) = p1;
    }
}

extern "C" void kernel_launch(void* const* d_in, const int* in_sizes, int n_in,
                              void* d_out, int out_size, void* d_ws, size_t ws_size,
                              hipStream_t stream) {
    const float* x      = (const float*)d_in[0];
    const float* w_attn = (const float*)d_in[1];
    const float* w_proj = (const float*)d_in[2];
    float* out = (float*)d_out;

    char* ws = (char*)d_ws;
    const size_t SZ_XB = (size_t)M_ * C_ * 2;       // 16.78 MB
    const size_t SZ_WA = (size_t)C_ * N1_ * 2;      //  6.29 MB
    const size_t SZ_WP = (size_t)C_ * C_ * 2;       //  2.10 MB
    const size_t SZ_QK = (size_t)M_ * NQK_ * 2;     // 33.55 MB
    const size_t SZ_VT = (size_t)M_ * C_ * 2;       // 16.78 MB
    u16* xb   = (u16*)ws;
    u16* waT  = (u16*)(ws + SZ_XB);
    u16* wpT  = (u16*)(ws + SZ_XB + SZ_WA);
    u16* qkb  = (u16*)(ws + SZ_XB + SZ_WA + SZ_WP);
    u16* vtb  = (u16*)(ws + SZ_XB + SZ_WA + SZ_WP + SZ_QK);
    u16* attO = (u16*)(ws + SZ_XB + SZ_WA + SZ_WP + SZ_QK + SZ_VT);

    f32_to_bf16_k<<<2048, 256, 0, stream>>>(x, xb, M_ * C_);
    dim3 tb(32, 8);
    // Q weights carry 0.125 * log2(e) so attention works in exp2 domain
    transpose_f32_bf16_k<<<dim3(N1_ / 32, C_ / 32), tb, 0, stream>>>(w_attn, waT, C_, N1_, C_,
                                                                     0.125f * 1.44269504088896f);
    transpose_f32_bf16_k<<<dim3(C_ / 32, C_ / 32), tb, 0, stream>>>(w_proj, wpT, C_, C_, 0, 1.0f);

    gemm_bt_k<2><<<dim3((M_ / 128) * (N1_ / 128)), 256, 0, stream>>>(xb, waT, qkb, vtb, M_, N1_, C_);
    attn_fwd_k<<<dim3(1024), 256, 0, stream>>>(qkb, vtb, attO);
    gemm_bt_k<0><<<dim3((M_ / 128) * (C_ / 128)), 256, 0, stream>>>(attO, wpT, out, nullptr, M_, C_, C_);
}